// Round 6
// baseline (147.494 us; speedup 1.0000x reference)
//
#include <hip/hip_runtime.h>
#include <hip/hip_cooperative_groups.h>

namespace cg = cooperative_groups;

#define DIM    256
#define NROWS  8192
#define NHALF  4096
#define NTILE  64                          // 8192 / 128 tiles per dim
#define NBLK   ((NTILE * (NTILE + 1)) / 2) // 2080 triangular tiles
#define MAXGRID 696                        // <= 256 CUs * 3 blocks/CU

using i32x4  = __attribute__((ext_vector_type(4))) int;
using i32x8  = __attribute__((ext_vector_type(8))) int;
using f32x16 = __attribute__((ext_vector_type(16))) float;

struct i32x8_pair { i32x4 lo, hi; };

// Single fused cooperative kernel:
//   phase 1: row-normalize x -> z8 (fp8 e4m3)
//   phase 2: Gram exp-sum over striped upper-triangular 128x128 tiles,
//            per-block local double accumulation (no atomics)
//   phase 3: block 0 reduces per-block partials, writes the loss.
__global__ __launch_bounds__(256, 3) void fused_k(const float* __restrict__ x,
                                                  unsigned char* __restrict__ z8,
                                                  double2* __restrict__ partial,
                                                  float* __restrict__ out) {
  cg::grid_group grid = cg::this_grid();

  __shared__ unsigned char As[128 * 128];   // 16 KB
  __shared__ unsigned char Bs[128 * 128];   // 16 KB
  __shared__ float red[8];

  const int tid   = threadIdx.x;
  const int lane  = tid & 63;
  const int w     = tid >> 6;
  const int wr    = w >> 1, wc = w & 1;     // 2x2 wave grid, 64x64 each
  const int l31   = lane & 31;
  const int khalf = lane >> 5;              // K-half selector for 32x32 frags

  // ---- phase 1: normalize (one wave per row, grid-strided) ----
  for (int row = blockIdx.x * 4 + w; row < NROWS; row += gridDim.x * 4) {
    float4 v = ((const float4*)(x + (size_t)row * DIM))[lane];
    float ss = v.x * v.x + v.y * v.y + v.z * v.z + v.w * v.w;
#pragma unroll
    for (int off = 32; off > 0; off >>= 1) ss += __shfl_xor(ss, off, 64);
    float rn = rsqrtf(fmaxf(ss, 1e-24f));
    int p = __builtin_amdgcn_cvt_pk_fp8_f32(v.x * rn, v.y * rn, 0, false);
    p     = __builtin_amdgcn_cvt_pk_fp8_f32(v.z * rn, v.w * rn, p, true);
    ((int*)(z8 + (size_t)row * DIM))[lane] = p;
  }

  grid.sync();

  // ---- phase 2: gram tiles, striped over the grid ----
  double Sloc = 0.0, ssloc = 0.0;
  for (int bid = blockIdx.x; bid < NBLK; bid += gridDim.x) {
    // linear tile id -> (bi, bj), bi <= bj
    int bi = (int)((129.0 - sqrt(129.0 * 129.0 - 8.0 * (double)bid)) * 0.5);
    while ((bi * (129 - bi)) / 2 > bid) --bi;
    while (((bi + 1) * (128 - bi)) / 2 <= bid) ++bi;
    const int bj = bi + (bid - (bi * (129 - bi)) / 2);

    const size_t rowA0 = (size_t)bi * 128;
    const size_t rowB0 = (size_t)bj * 128;

    f32x16 acc_f[2][2] = {};

    for (int kb = 0; kb < 2; ++kb) {        // two BK=128 staging rounds
      // stage 128 rows x 128 fp8 bytes for A and B via global_load_lds,
      // 16B/lane. LDS colblock cb holds global colblock cb ^ (row&7)
      // (swizzle on the global side: glds dest = uniform base + lane*16).
#pragma unroll
      for (int i = 0; i < 4; ++i) {
        int c   = i * 256 + tid;            // 0..1023 -> (row, colblock)
        int row = c >> 3;                   // 0..127
        int cb  = c & 7;
        int gcb = cb ^ (row & 7);
        const unsigned char* ga = z8 + (rowA0 + row) * DIM + kb * 128 + gcb * 16;
        const unsigned char* gb = z8 + (rowB0 + row) * DIM + kb * 128 + gcb * 16;
        __builtin_amdgcn_global_load_lds(
            (const __attribute__((address_space(1))) void*)ga,
            (__attribute__((address_space(3))) void*)&As[(size_t)(i * 256 + (tid & ~63)) * 16],
            16, 0, 0);
        __builtin_amdgcn_global_load_lds(
            (const __attribute__((address_space(1))) void*)gb,
            (__attribute__((address_space(3))) void*)&Bs[(size_t)(i * 256 + (tid & ~63)) * 16],
            16, 0, 0);
      }
      __syncthreads();

#pragma unroll
      for (int kc = 0; kc < 2; ++kc) {      // two K=64 MFMA chunks per round
        i32x8 a[2], b[2];
#pragma unroll
        for (int t = 0; t < 2; ++t) {
          const int cb0 = kc * 4 + khalf * 2;
          int mr = wr * 64 + t * 32 + l31;
          i32x8_pair pa = { *(const i32x4*)&As[mr * 128 + ((cb0    ) ^ (mr & 7)) * 16],
                            *(const i32x4*)&As[mr * 128 + ((cb0 + 1) ^ (mr & 7)) * 16] };
          a[t] = __builtin_bit_cast(i32x8, pa);
          int nr = wc * 64 + t * 32 + l31;
          i32x8_pair pb = { *(const i32x4*)&Bs[nr * 128 + ((cb0    ) ^ (nr & 7)) * 16],
                            *(const i32x4*)&Bs[nr * 128 + ((cb0 + 1) ^ (nr & 7)) * 16] };
          b[t] = __builtin_bit_cast(i32x8, pb);
        }
#pragma unroll
        for (int ti = 0; ti < 2; ++ti)
#pragma unroll
          for (int tj = 0; tj < 2; ++tj)
            acc_f[ti][tj] = __builtin_amdgcn_mfma_scale_f32_32x32x64_f8f6f4(
                a[ti], b[tj], acc_f[ti][tj],
                0, 0,                       // fp8 e4m3 A and B
                0, 0x7f7f7f7f,              // scale_a = 1.0 (E8M0 127)
                0, 0x7f7f7f7f);             // scale_b = 1.0
      }
      __syncthreads();
    }

    // epilogue: exp(cos/TEMP), TEMP = 2. Uniform-branch diagonal handling.
    const bool tdiag = (bi == bj);          // true diagonal tile
    const bool sdiag = (bj == bi + 32);     // (i, i+4096) sim_s tile
    float lsum = 0.0f, dsum = 0.0f;
    if (tdiag || sdiag) {
#pragma unroll
      for (int ti = 0; ti < 2; ++ti)
#pragma unroll
        for (int tj = 0; tj < 2; ++tj)
#pragma unroll
          for (int r = 0; r < 16; ++r) {
            float e = __expf(acc_f[ti][tj][r] * 0.5f);
            lsum += e;
            // 32x32 C/D: col = lane&31, row = (reg&3) + 8*(reg>>2) + 4*khalf
            int row_l = (r & 3) + 8 * (r >> 2) + 4 * khalf;
            if (wr == wc && ti == tj && row_l == l31) dsum += e;
          }
    } else {
#pragma unroll
      for (int ti = 0; ti < 2; ++ti)
#pragma unroll
        for (int tj = 0; tj < 2; ++tj)
#pragma unroll
          for (int r = 0; r < 16; ++r)
            lsum += __expf(acc_f[ti][tj][r] * 0.5f);
    }
#pragma unroll
    for (int off = 32; off > 0; off >>= 1) lsum += __shfl_xor(lsum, off, 64);
    if (tdiag || sdiag) {
#pragma unroll
      for (int off = 32; off > 0; off >>= 1) dsum += __shfl_xor(dsum, off, 64);
    }
    if (lane == 0) { red[w] = lsum; red[4 + w] = dsum; }
    __syncthreads();

    if (tid == 0) {
      float l  = red[0] + red[1] + red[2] + red[3];
      float dd = red[4] + red[5] + red[6] + red[7];
      // S accumulates T_full + all_diag: diag tile contributes lsum + diag
      // extra, off-diag tile counts twice by symmetry.
      Sloc  += tdiag ? (double)l + (double)dd : 2.0 * (double)l;
      if (sdiag) ssloc += (double)dd;
    }
    __syncthreads();   // red[] reuse + LDS tile reuse across iterations
  }

  if (tid == 0) {
    double2 v; v.x = Sloc; v.y = ssloc;
    partial[blockIdx.x] = v;                // unique slot, plain store
  }

  grid.sync();

  // ---- phase 3: block 0 reduces per-block partials ----
  if (blockIdx.x == 0) {
    double* redS = (double*)As;             // reuse LDS
    double* redD = (double*)Bs;
    double s = 0.0, ss = 0.0;
    for (int i = tid; i < (int)gridDim.x; i += 256) {
      double2 v = partial[i];
      s += v.x; ss += v.y;
    }
#pragma unroll
    for (int off = 32; off > 0; off >>= 1) {
      s  += __shfl_xor(s,  off, 64);
      ss += __shfl_xor(ss, off, 64);
    }
    if (lane == 0) { redS[w] = s; redD[w] = ss; }
    __syncthreads();
    if (tid == 0) {
      double S  = redS[0] + redS[1] + redS[2] + redS[3];
      double sd = redD[0] + redD[1] + redD[2] + redD[3];
      out[0] = (float)(log(0.5 * S + sd) - log(sd));
    }
  }
}

extern "C" void kernel_launch(void* const* d_in, const int* in_sizes, int n_in,
                              void* d_out, int out_size, void* d_ws, size_t ws_size,
                              hipStream_t stream) {
  const float* x    = (const float*)d_in[0];
  unsigned char* z8 = (unsigned char*)d_ws;                  // 8192*256 fp8 = 2 MB
  double2* partial  = (double2*)((char*)d_ws + (size_t)NROWS * DIM);  // MAXGRID * 16 B
  float* out        = (float*)d_out;

  // Pick the largest co-resident grid the runtime will accept (cached; the
  // first, uncaptured correctness call computes it).
  static int grid_blocks = 0;
  if (grid_blocks == 0) {
    int nb = 0;
    if (hipOccupancyMaxActiveBlocksPerMultiprocessor(&nb, (const void*)fused_k,
                                                     256, 0) != hipSuccess || nb < 1)
      nb = 1;
    long cap = (long)nb * 256;               // 256 CUs on MI355X
    grid_blocks = (int)(cap < MAXGRID ? cap : MAXGRID);
  }

  void* args[] = { (void*)&x, (void*)&z8, (void*)&partial, (void*)&out };
  hipLaunchCooperativeKernel((void*)fused_k, dim3(grid_blocks), dim3(256),
                             args, 0, stream);
}

// Round 7
// 83.593 us; speedup vs baseline: 1.7644x; 1.7644x over previous
//
#include <hip/hip_runtime.h>

#define DIM    256
#define NROWS  8192
#define NHALF  4096
#define NT64   128                          // 64-row tiles per dim
#define NWT    ((NT64 * (NT64 + 1)) / 2)    // 8256 triangular wave-tiles
#define GRID   (NWT / 4)                    // 2064 blocks, 1 tile per wave

using i32x4  = __attribute__((ext_vector_type(4))) int;
using i32x8  = __attribute__((ext_vector_type(8))) int;
using f32x16 = __attribute__((ext_vector_type(16))) float;

struct i32x8_pair { i32x4 lo, hi; };

// ---- kernel 1: row-normalize x (fp32) -> z8 (fp8 e4m3), one wave per row.
__global__ __launch_bounds__(256) void normalize_k(const float* __restrict__ x,
                                                   unsigned char* __restrict__ z8) {
  const int row  = blockIdx.x * 4 + (threadIdx.x >> 6);
  const int lane = threadIdx.x & 63;
  float4 v = ((const float4*)(x + (size_t)row * DIM))[lane];
  float ss = v.x * v.x + v.y * v.y + v.z * v.z + v.w * v.w;
#pragma unroll
  for (int off = 32; off > 0; off >>= 1) ss += __shfl_xor(ss, off, 64);
  float rn = rsqrtf(fmaxf(ss, 1e-24f));
  int p = __builtin_amdgcn_cvt_pk_fp8_f32(v.x * rn, v.y * rn, 0, false);
  p     = __builtin_amdgcn_cvt_pk_fp8_f32(v.z * rn, v.w * rn, p, true);
  ((int*)(z8 + (size_t)row * DIM))[lane] = p;
}

// ---- kernel 2: Gram exp-sum, WAVE-AUTONOMOUS 64x64 tiles, MX-fp8.
// Each wave stages its own 16 KB (A 64x128B + B 64x128B per kb round) into
// private LDS via global_load_lds and waits with its OWN s_waitcnt vmcnt(0)
// (no __syncthreads in the hot path -> no cross-wave barrier drains).
__global__ __launch_bounds__(256, 2) void gram_k(const unsigned char* __restrict__ z8,
                                                 double2* __restrict__ partial) {
  __shared__ unsigned char buf[4][16384];   // per-wave A(8K)+B(8K)
  __shared__ double redS[4], redD[4];

  const int tid   = threadIdx.x;
  const int lane  = tid & 63;
  const int w     = tid >> 6;
  const int l31   = lane & 31;
  const int khalf = lane >> 5;              // K-half selector for 32x32 frags

  // wave-tile id -> (bi, bj), bi <= bj, on the 128x128 tile grid
  const int id = blockIdx.x * 4 + w;
  int bi = (int)((257.0 - sqrt(257.0 * 257.0 - 8.0 * (double)id)) * 0.5);
  while ((bi * (257 - bi)) / 2 > id) --bi;
  while (((bi + 1) * (256 - bi)) / 2 <= id) ++bi;
  const int bj = bi + (id - (bi * (257 - bi)) / 2);

  const size_t rowA0 = (size_t)bi * 64;
  const size_t rowB0 = (size_t)bj * 64;

  unsigned char* Aw = &buf[w][0];
  unsigned char* Bw = &buf[w][8192];

  // staging lane map: 1 KB per glds = 8 rows x 128 B; lane -> (row-in-8, chunk)
  const int r8 = lane >> 3;                 // 0..7
  const int c8 = lane & 7;                  // 0..7
  const int sw = c8 ^ r8;                   // XOR swizzle (row&7 == r8)

  f32x16 acc_f[2][2] = {};

  for (int kb = 0; kb < 2; ++kb) {          // two BK=128 rounds, same buffer
    const unsigned char* gA = z8 + (rowA0 + r8) * DIM + kb * 128 + sw * 16;
    const unsigned char* gB = z8 + (rowB0 + r8) * DIM + kb * 128 + sw * 16;
#pragma unroll
    for (int g = 0; g < 8; ++g) {
      __builtin_amdgcn_global_load_lds(
          (const __attribute__((address_space(1))) void*)(gA + (size_t)g * 8 * DIM),
          (__attribute__((address_space(3))) void*)(Aw + g * 1024), 16, 0, 0);
      __builtin_amdgcn_global_load_lds(
          (const __attribute__((address_space(1))) void*)(gB + (size_t)g * 8 * DIM),
          (__attribute__((address_space(3))) void*)(Bw + g * 1024), 16, 0, 0);
    }
    // wave-private wait: only THIS wave's staging loads
    __asm__ __volatile__("s_waitcnt vmcnt(0)" ::: "memory");

#pragma unroll
    for (int kc = 0; kc < 2; ++kc) {        // two K=64 MFMA chunks per round
      const int cb0 = kc * 4 + khalf * 2;   // first 16B chunk of lane's 32B
      i32x8 a[2], b[2];
#pragma unroll
      for (int t = 0; t < 2; ++t) {
        int r = t * 32 + l31;
        i32x8_pair pa = { *(const i32x4*)&Aw[r * 128 + ((cb0    ) ^ (r & 7)) * 16],
                          *(const i32x4*)&Aw[r * 128 + ((cb0 + 1) ^ (r & 7)) * 16] };
        a[t] = __builtin_bit_cast(i32x8, pa);
        i32x8_pair pb = { *(const i32x4*)&Bw[r * 128 + ((cb0    ) ^ (r & 7)) * 16],
                          *(const i32x4*)&Bw[r * 128 + ((cb0 + 1) ^ (r & 7)) * 16] };
        b[t] = __builtin_bit_cast(i32x8, pb);
      }
#pragma unroll
      for (int ti = 0; ti < 2; ++ti)
#pragma unroll
        for (int tj = 0; tj < 2; ++tj)
          acc_f[ti][tj] = __builtin_amdgcn_mfma_scale_f32_32x32x64_f8f6f4(
              a[ti], b[tj], acc_f[ti][tj],
              0, 0,                         // fp8 e4m3 A and B
              0, 0x7f7f7f7f,                // scale_a = 1.0 (E8M0 127)
              0, 0x7f7f7f7f);               // scale_b = 1.0
    }
    // all ds_reads retired before next kb's glds overwrite the buffer
    __asm__ __volatile__("s_waitcnt lgkmcnt(0)" ::: "memory");
  }

  // epilogue: exp(cos/TEMP), TEMP = 2. Wave-uniform diagonal branches.
  const bool tdiag = (bi == bj);            // true diagonal tile
  const bool sdiag = (bj == bi + 64);       // (i, i+4096) sim_s tile
  float lsum = 0.0f, dsum = 0.0f;
  if (tdiag || sdiag) {
#pragma unroll
    for (int ti = 0; ti < 2; ++ti)
#pragma unroll
      for (int tj = 0; tj < 2; ++tj)
#pragma unroll
        for (int r = 0; r < 16; ++r) {
          float e = __expf(acc_f[ti][tj][r] * 0.5f);
          lsum += e;
          // 32x32 C/D: col = lane&31, row = (reg&3) + 8*(reg>>2) + 4*khalf
          int row_l = (r & 3) + 8 * (r >> 2) + 4 * khalf;
          if (ti == tj && row_l == l31) dsum += e;
        }
  } else {
#pragma unroll
    for (int ti = 0; ti < 2; ++ti)
#pragma unroll
      for (int tj = 0; tj < 2; ++tj)
#pragma unroll
        for (int r = 0; r < 16; ++r)
          lsum += __expf(acc_f[ti][tj][r] * 0.5f);
  }
#pragma unroll
  for (int off = 32; off > 0; off >>= 1) lsum += __shfl_xor(lsum, off, 64);
  if (tdiag || sdiag) {
#pragma unroll
    for (int off = 32; off > 0; off >>= 1) dsum += __shfl_xor(dsum, off, 64);
  }

  // one barrier per block (end of life): combine the 4 wave partials.
  if (lane == 0) {
    // S accumulates T_full + all_diag: diag tile contributes lsum + diag
    // extra, off-diag tile counts twice by symmetry.
    redS[w] = tdiag ? (double)lsum + (double)dsum : 2.0 * (double)lsum;
    redD[w] = sdiag ? (double)dsum : 0.0;
  }
  __syncthreads();
  if (tid == 0) {
    double2 v;
    v.x = redS[0] + redS[1] + redS[2] + redS[3];
    v.y = redD[0] + redD[1] + redD[2] + redD[3];
    partial[blockIdx.x] = v;                // unique slot: plain store, no RMW
  }
}

// ---- kernel 3: reduce 2064 partials, compute the loss. One block.
__global__ __launch_bounds__(256) void reduce_k(const double2* __restrict__ partial,
                                                float* __restrict__ out) {
  __shared__ double redS[4], redD[4];
  double s = 0.0, ss = 0.0;
  for (int i = threadIdx.x; i < GRID; i += 256) {
    double2 v = partial[i];
    s += v.x; ss += v.y;
  }
#pragma unroll
  for (int off = 32; off > 0; off >>= 1) {
    s  += __shfl_xor(s,  off, 64);
    ss += __shfl_xor(ss, off, 64);
  }
  const int w = threadIdx.x >> 6;
  if ((threadIdx.x & 63) == 0) { redS[w] = s; redD[w] = ss; }
  __syncthreads();
  if (threadIdx.x == 0) {
    double S  = redS[0] + redS[1] + redS[2] + redS[3];
    double sd = redD[0] + redD[1] + redD[2] + redD[3];
    out[0] = (float)(log(0.5 * S + sd) - log(sd));
  }
}

extern "C" void kernel_launch(void* const* d_in, const int* in_sizes, int n_in,
                              void* d_out, int out_size, void* d_ws, size_t ws_size,
                              hipStream_t stream) {
  const float* x    = (const float*)d_in[0];
  unsigned char* z8 = (unsigned char*)d_ws;                  // 8192*256 fp8 = 2 MB
  double2* partial  = (double2*)((char*)d_ws + (size_t)NROWS * DIM);  // GRID * 16 B
  float* out        = (float*)d_out;

  normalize_k<<<dim3(NROWS / 4), dim3(256), 0, stream>>>(x, z8);
  gram_k<<<dim3(GRID), dim3(256), 0, stream>>>(z8, partial);
  reduce_k<<<dim3(1), dim3(256), 0, stream>>>(partial, out);
}

// Round 8
// 81.807 us; speedup vs baseline: 1.8030x; 1.0218x over previous
//
#include <hip/hip_runtime.h>

#define DIM    256
#define NROWS  8192
#define NHALF  4096
#define NTILE  64                          // 8192 / 128 tiles per dim
#define NBLK   ((NTILE * (NTILE + 1)) / 2) // 2080 triangular tiles

using i32x4  = __attribute__((ext_vector_type(4))) int;
using i32x8  = __attribute__((ext_vector_type(8))) int;
using f32x16 = __attribute__((ext_vector_type(16))) float;

struct i32x8_pair { i32x4 lo, hi; };

// ---- kernel 1: row-normalize x (fp32) -> z8 (fp8 e4m3), one wave per row.
__global__ __launch_bounds__(256) void normalize_k(const float* __restrict__ x,
                                                   unsigned char* __restrict__ z8) {
  const int row  = blockIdx.x * 4 + (threadIdx.x >> 6);
  const int lane = threadIdx.x & 63;
  float4 v = ((const float4*)(x + (size_t)row * DIM))[lane];
  float ss = v.x * v.x + v.y * v.y + v.z * v.z + v.w * v.w;
#pragma unroll
  for (int off = 32; off > 0; off >>= 1) ss += __shfl_xor(ss, off, 64);
  float rn = rsqrtf(fmaxf(ss, 1e-24f));
  int p = __builtin_amdgcn_cvt_pk_fp8_f32(v.x * rn, v.y * rn, 0, false);
  p     = __builtin_amdgcn_cvt_pk_fp8_f32(v.z * rn, v.w * rn, p, true);
  ((int*)(z8 + (size_t)row * DIM))[lane] = p;
}

// ---- kernel 2: Gram exp-sum over upper-triangular 128x128 tiles, MX-fp8.
// SINGLE K=256 staging round -> exactly one mid-kernel barrier. Plain-store
// per-block partials (no atomics).
__global__ __launch_bounds__(256, 2) void gram_k(const unsigned char* __restrict__ z8,
                                                 double2* __restrict__ partial) {
  __shared__ unsigned char As[128 * 256];   // 32 KB
  __shared__ unsigned char Bs[128 * 256];   // 32 KB
  __shared__ float red[8];

  // linear block id -> (bi, bj), bi <= bj
  const int bid = blockIdx.x;
  int bi = (int)((129.0 - sqrt(129.0 * 129.0 - 8.0 * (double)bid)) * 0.5);
  while ((bi * (129 - bi)) / 2 > bid) --bi;
  while (((bi + 1) * (128 - bi)) / 2 <= bid) ++bi;
  const int bj = bi + (bid - (bi * (129 - bi)) / 2);

  const int tid   = threadIdx.x;
  const int lane  = tid & 63;
  const int w     = tid >> 6;
  const int wr    = w >> 1, wc = w & 1;     // 2x2 wave grid, 64x64 each
  const int l31   = lane & 31;
  const int khalf = lane >> 5;              // K-half selector for 32x32 frags

  const size_t rowA0 = (size_t)bi * 128;
  const size_t rowB0 = (size_t)bj * 128;

  // stage full 128x256B A and B tiles via global_load_lds, 16B/lane.
  // LDS 16B-chunk cb holds global chunk (cb&8) | ((cb&7) ^ (row&7))
  // (swizzle on the global side: glds dest = wave-uniform base + lane*16).
#pragma unroll
  for (int i = 0; i < 8; ++i) {
    int c   = i * 256 + tid;                // 0..2047 -> (row, chunk)
    int row = c >> 4;                       // 0..127
    int cb  = c & 15;
    int gcb = (cb & 8) | ((cb & 7) ^ (row & 7));
    const unsigned char* ga = z8 + (rowA0 + row) * DIM + gcb * 16;
    const unsigned char* gb = z8 + (rowB0 + row) * DIM + gcb * 16;
    __builtin_amdgcn_global_load_lds(
        (const __attribute__((address_space(1))) void*)ga,
        (__attribute__((address_space(3))) void*)&As[(size_t)(i * 256 + (tid & ~63)) * 16],
        16, 0, 0);
    __builtin_amdgcn_global_load_lds(
        (const __attribute__((address_space(1))) void*)gb,
        (__attribute__((address_space(3))) void*)&Bs[(size_t)(i * 256 + (tid & ~63)) * 16],
        16, 0, 0);
  }
  __syncthreads();                          // the ONLY mid-kernel barrier

  f32x16 acc_f[2][2] = {};
#pragma unroll
  for (int kc = 0; kc < 4; ++kc) {          // four K=64 MFMA chunks
    const int cb0 = kc * 4 + khalf * 2;     // even; +1 stays in same 8-group
    i32x8 a[2], b[2];
#pragma unroll
    for (int t = 0; t < 2; ++t) {
      int mr = wr * 64 + t * 32 + l31;
      int c0 = (cb0 & 8) | ((cb0 & 7) ^ (mr & 7));
      int c1 = (cb0 & 8) | (((cb0 + 1) & 7) ^ (mr & 7));
      i32x8_pair pa = { *(const i32x4*)&As[mr * 256 + c0 * 16],
                        *(const i32x4*)&As[mr * 256 + c1 * 16] };
      a[t] = __builtin_bit_cast(i32x8, pa);
      int nr = wc * 64 + t * 32 + l31;
      int d0 = (cb0 & 8) | ((cb0 & 7) ^ (nr & 7));
      int d1 = (cb0 & 8) | (((cb0 + 1) & 7) ^ (nr & 7));
      i32x8_pair pb = { *(const i32x4*)&Bs[nr * 256 + d0 * 16],
                        *(const i32x4*)&Bs[nr * 256 + d1 * 16] };
      b[t] = __builtin_bit_cast(i32x8, pb);
    }
#pragma unroll
    for (int ti = 0; ti < 2; ++ti)
#pragma unroll
      for (int tj = 0; tj < 2; ++tj)
        acc_f[ti][tj] = __builtin_amdgcn_mfma_scale_f32_32x32x64_f8f6f4(
            a[ti], b[tj], acc_f[ti][tj],
            0, 0,                           // fp8 e4m3 A and B
            0, 0x7f7f7f7f,                  // scale_a = 1.0 (E8M0 127)
            0, 0x7f7f7f7f);                 // scale_b = 1.0
  }

  // epilogue: exp(cos/TEMP), TEMP = 2. Uniform-branch diagonal handling.
  const bool tdiag = (bi == bj);            // true diagonal tile
  const bool sdiag = (bj == bi + 32);       // (i, i+4096) sim_s tile
  float lsum = 0.0f, dsum = 0.0f;
  if (tdiag || sdiag) {
#pragma unroll
    for (int ti = 0; ti < 2; ++ti)
#pragma unroll
      for (int tj = 0; tj < 2; ++tj)
#pragma unroll
        for (int r = 0; r < 16; ++r) {
          float e = __expf(acc_f[ti][tj][r] * 0.5f);
          lsum += e;
          // 32x32 C/D: col = lane&31, row = (reg&3) + 8*(reg>>2) + 4*khalf
          int row_l = (r & 3) + 8 * (r >> 2) + 4 * khalf;
          if (wr == wc && ti == tj && row_l == l31) dsum += e;
        }
  } else {
#pragma unroll
    for (int ti = 0; ti < 2; ++ti)
#pragma unroll
      for (int tj = 0; tj < 2; ++tj)
#pragma unroll
        for (int r = 0; r < 16; ++r)
          lsum += __expf(acc_f[ti][tj][r] * 0.5f);
  }
#pragma unroll
  for (int off = 32; off > 0; off >>= 1) lsum += __shfl_xor(lsum, off, 64);
  if (tdiag || sdiag) {
#pragma unroll
    for (int off = 32; off > 0; off >>= 1) dsum += __shfl_xor(dsum, off, 64);
  }
  if (lane == 0) { red[w] = lsum; red[4 + w] = dsum; }
  __syncthreads();

  if (tid == 0) {
    float l  = red[0] + red[1] + red[2] + red[3];
    float dd = red[4] + red[5] + red[6] + red[7];
    // S accumulates T_full + all_diag: diag tile contributes lsum + diag
    // extra, off-diag tile counts twice by symmetry.
    double2 v;
    v.x = tdiag ? (double)l + (double)dd : 2.0 * (double)l;
    v.y = sdiag ? (double)dd : 0.0;
    partial[bid] = v;                       // unique slot: plain store, no RMW
  }
}

// ---- kernel 3: reduce 2080 partials, compute the loss. One block.
__global__ __launch_bounds__(256) void reduce_k(const double2* __restrict__ partial,
                                                float* __restrict__ out) {
  __shared__ double redS[4], redD[4];
  double s = 0.0, ss = 0.0;
  for (int i = threadIdx.x; i < NBLK; i += 256) {
    double2 v = partial[i];
    s += v.x; ss += v.y;
  }
#pragma unroll
  for (int off = 32; off > 0; off >>= 1) {
    s  += __shfl_xor(s,  off, 64);
    ss += __shfl_xor(ss, off, 64);
  }
  const int w = threadIdx.x >> 6;
  if ((threadIdx.x & 63) == 0) { redS[w] = s; redD[w] = ss; }
  __syncthreads();
  if (threadIdx.x == 0) {
    double S  = redS[0] + redS[1] + redS[2] + redS[3];
    double sd = redD[0] + redD[1] + redD[2] + redD[3];
    out[0] = (float)(log(0.5 * S + sd) - log(sd));
  }
}

extern "C" void kernel_launch(void* const* d_in, const int* in_sizes, int n_in,
                              void* d_out, int out_size, void* d_ws, size_t ws_size,
                              hipStream_t stream) {
  const float* x    = (const float*)d_in[0];
  unsigned char* z8 = (unsigned char*)d_ws;                  // 8192*256 fp8 = 2 MB
  double2* partial  = (double2*)((char*)d_ws + (size_t)NROWS * DIM);  // 2080 * 16 B
  float* out        = (float*)d_out;

  normalize_k<<<dim3(NROWS / 4), dim3(256), 0, stream>>>(x, z8);
  gram_k<<<dim3(NBLK), dim3(256), 0, stream>>>(z8, partial);
  reduce_k<<<dim3(1), dim3(256), 0, stream>>>(partial, out);
}

// Round 9
// 75.204 us; speedup vs baseline: 1.9613x; 1.0878x over previous
//
#include <hip/hip_runtime.h>

#define DIM    256
#define NROWS  8192
#define NHALF  4096
#define NTILE  64                          // 8192 / 128 tiles per dim
#define NBLK   ((NTILE * (NTILE + 1)) / 2) // 2080 triangular tiles
#define RSTRIDE 128                        // z4 row stride in bytes (256 fp4)

using i32x4  = __attribute__((ext_vector_type(4))) int;
using i32x8  = __attribute__((ext_vector_type(8))) int;
using f32x16 = __attribute__((ext_vector_type(16))) float;

struct i32x8_pair { i32x4 lo, hi; };

// fp4 e2m1 RNE quantizer for pre-scaled input (representable {0,.5,1,1.5,2,3,4,6})
__device__ __forceinline__ unsigned fp4q(float v) {
  float a = fabsf(v);
  unsigned s = (__builtin_bit_cast(unsigned, v) >> 31) << 3;
  unsigned c = a < 0.25f ? 0u : a < 0.75f ? 1u : a < 1.25f ? 2u : a < 1.75f ? 3u
             : a < 2.50f ? 4u : a < 3.50f ? 5u : a < 5.00f ? 6u : 7u;
  return s | c;
}

// ---- kernel 1: row-normalize x (fp32) -> z4 (fp4 e2m1, x16 scale), 1 wave/row.
__global__ __launch_bounds__(256) void normalize_k(const float* __restrict__ x,
                                                   unsigned char* __restrict__ z4) {
  const int row  = blockIdx.x * 4 + (threadIdx.x >> 6);
  const int lane = threadIdx.x & 63;
  float4 v = ((const float4*)(x + (size_t)row * DIM))[lane];
  float ss = v.x * v.x + v.y * v.y + v.z * v.z + v.w * v.w;
#pragma unroll
  for (int off = 32; off > 0; off >>= 1) ss += __shfl_xor(ss, off, 64);
  float rn = rsqrtf(fmaxf(ss, 1e-24f)) * 16.0f;   // pre-apply 2^4 (MX scale 2^-4)
  unsigned c0 = fp4q(v.x * rn), c1 = fp4q(v.y * rn);
  unsigned c2 = fp4q(v.z * rn), c3 = fp4q(v.w * rn);
  // element 2i in low nibble, 2i+1 in high nibble; lane covers elems 4l..4l+3
  unsigned short pk = (unsigned short)((c0 | (c1 << 4)) | ((c2 | (c3 << 4)) << 8));
  ((unsigned short*)(z4 + (size_t)row * RSTRIDE))[lane] = pk;
}

// ---- kernel 2: Gram exp-sum over upper-triangular 128x128 tiles, MX-fp4.
// Full K=256 staged in ONE round (A+B = 32 KB -> 4 blocks/CU, one barrier).
__global__ __launch_bounds__(256, 4) void gram_k(const unsigned char* __restrict__ z4,
                                                 double2* __restrict__ partial) {
  __shared__ unsigned char As[128 * RSTRIDE];   // 16 KB
  __shared__ unsigned char Bs[128 * RSTRIDE];   // 16 KB
  __shared__ float red[8];

  // linear block id -> (bi, bj), bi <= bj
  const int bid = blockIdx.x;
  int bi = (int)((129.0 - sqrt(129.0 * 129.0 - 8.0 * (double)bid)) * 0.5);
  while ((bi * (129 - bi)) / 2 > bid) --bi;
  while (((bi + 1) * (128 - bi)) / 2 <= bid) ++bi;
  const int bj = bi + (bid - (bi * (129 - bi)) / 2);

  const int tid   = threadIdx.x;
  const int lane  = tid & 63;
  const int w     = tid >> 6;
  const int wr    = w >> 1, wc = w & 1;     // 2x2 wave grid, 64x64 each
  const int l31   = lane & 31;
  const int khalf = lane >> 5;              // K-half selector for 32x32 frags

  const size_t rowA0 = (size_t)bi * 128;
  const size_t rowB0 = (size_t)bj * 128;

  // stage 128 rows x 128 B (fp4) for A and B via global_load_lds, 16B/lane.
  // LDS 16B-chunk cb holds global chunk cb ^ (row&7) (swizzle applied on the
  // global side: glds dest = wave-uniform base + lane*16). 8 chunks/row.
#pragma unroll
  for (int i = 0; i < 4; ++i) {
    int c   = i * 256 + tid;                // 0..1023 -> (row, chunk)
    int row = c >> 3;                       // 0..127
    int cb  = c & 7;
    int gcb = cb ^ (row & 7);
    const unsigned char* ga = z4 + (rowA0 + row) * RSTRIDE + gcb * 16;
    const unsigned char* gb = z4 + (rowB0 + row) * RSTRIDE + gcb * 16;
    __builtin_amdgcn_global_load_lds(
        (const __attribute__((address_space(1))) void*)ga,
        (__attribute__((address_space(3))) void*)&As[(size_t)(i * 256 + (tid & ~63)) * 16],
        16, 0, 0);
    __builtin_amdgcn_global_load_lds(
        (const __attribute__((address_space(1))) void*)gb,
        (__attribute__((address_space(3))) void*)&Bs[(size_t)(i * 256 + (tid & ~63)) * 16],
        16, 0, 0);
  }
  __syncthreads();                          // the only mid-kernel barrier

  f32x16 acc_f[2][2] = {};
  const i32x4 zero4 = {0, 0, 0, 0};
#pragma unroll
  for (int kc = 0; kc < 4; ++kc) {          // four K=64 MFMA chunks
    // fp4: each lane's 32 K-elements = ONE 16B chunk; chunk id = kc*2 + khalf
    const int ch = kc * 2 + khalf;
    i32x8 a[2], b[2];
#pragma unroll
    for (int t = 0; t < 2; ++t) {
      int mr = wr * 64 + t * 32 + l31;
      i32x8_pair pa = { *(const i32x4*)&As[mr * RSTRIDE + (ch ^ (mr & 7)) * 16], zero4 };
      a[t] = __builtin_bit_cast(i32x8, pa); // fp4 reads only low 4 regs
      int nr = wc * 64 + t * 32 + l31;
      i32x8_pair pb = { *(const i32x4*)&Bs[nr * RSTRIDE + (ch ^ (nr & 7)) * 16], zero4 };
      b[t] = __builtin_bit_cast(i32x8, pb);
    }
#pragma unroll
    for (int ti = 0; ti < 2; ++ti)
#pragma unroll
      for (int tj = 0; tj < 2; ++tj)
        acc_f[ti][tj] = __builtin_amdgcn_mfma_scale_f32_32x32x64_f8f6f4(
            a[ti], b[tj], acc_f[ti][tj],
            4, 4,                           // FMT: fp4 e2m1 A and B
            0, 0x7B7B7B7B,                  // scale_a = 2^-4 (E8M0 123)
            0, 0x7B7B7B7B);                 // scale_b = 2^-4
  }

  // epilogue: exp(cos/TEMP), TEMP = 2. Uniform-branch diagonal handling.
  const bool tdiag = (bi == bj);            // true diagonal tile
  const bool sdiag = (bj == bi + 32);       // (i, i+4096) sim_s tile
  float lsum = 0.0f, dsum = 0.0f;
  if (tdiag || sdiag) {
#pragma unroll
    for (int ti = 0; ti < 2; ++ti)
#pragma unroll
      for (int tj = 0; tj < 2; ++tj)
#pragma unroll
        for (int r = 0; r < 16; ++r) {
          float e = __expf(acc_f[ti][tj][r] * 0.5f);
          lsum += e;
          // 32x32 C/D: col = lane&31, row = (reg&3) + 8*(reg>>2) + 4*khalf
          int row_l = (r & 3) + 8 * (r >> 2) + 4 * khalf;
          if (wr == wc && ti == tj && row_l == l31) dsum += e;
        }
  } else {
#pragma unroll
    for (int ti = 0; ti < 2; ++ti)
#pragma unroll
      for (int tj = 0; tj < 2; ++tj)
#pragma unroll
        for (int r = 0; r < 16; ++r)
          lsum += __expf(acc_f[ti][tj][r] * 0.5f);
  }
#pragma unroll
  for (int off = 32; off > 0; off >>= 1) lsum += __shfl_xor(lsum, off, 64);
  if (tdiag || sdiag) {
#pragma unroll
    for (int off = 32; off > 0; off >>= 1) dsum += __shfl_xor(dsum, off, 64);
  }
  if (lane == 0) { red[w] = lsum; red[4 + w] = dsum; }
  __syncthreads();

  if (tid == 0) {
    float l  = red[0] + red[1] + red[2] + red[3];
    float dd = red[4] + red[5] + red[6] + red[7];
    // S accumulates T_full + all_diag: diag tile contributes lsum + diag
    // extra, off-diag tile counts twice by symmetry.
    double2 v;
    v.x = tdiag ? (double)l + (double)dd : 2.0 * (double)l;
    v.y = sdiag ? (double)dd : 0.0;
    partial[bid] = v;                       // unique slot: plain store, no RMW
  }
}

// ---- kernel 3: reduce 2080 partials, compute the loss. One block.
__global__ __launch_bounds__(256) void reduce_k(const double2* __restrict__ partial,
                                               float* __restrict__ out) {
  __shared__ double redS[4], redD[4];
  double s = 0.0, ss = 0.0;
  for (int i = threadIdx.x; i < NBLK; i += 256) {
    double2 v = partial[i];
    s += v.x; ss += v.y;
  }
#pragma unroll
  for (int off = 32; off > 0; off >>= 1) {
    s  += __shfl_xor(s,  off, 64);
    ss += __shfl_xor(ss, off, 64);
  }
  const int w = threadIdx.x >> 6;
  if ((threadIdx.x & 63) == 0) { redS[w] = s; redD[w] = ss; }
  __syncthreads();
  if (threadIdx.x == 0) {
    double S  = redS[0] + redS[1] + redS[2] + redS[3];
    double sd = redD[0] + redD[1] + redD[2] + redD[3];
    out[0] = (float)(log(0.5 * S + sd) - log(sd));
  }
}

extern "C" void kernel_launch(void* const* d_in, const int* in_sizes, int n_in,
                              void* d_out, int out_size, void* d_ws, size_t ws_size,
                              hipStream_t stream) {
  const float* x    = (const float*)d_in[0];
  unsigned char* z4 = (unsigned char*)d_ws;                  // 8192*128 B = 1 MB
  double2* partial  = (double2*)((char*)d_ws + (size_t)NROWS * RSTRIDE);  // 2080*16 B
  float* out        = (float*)d_out;

  normalize_k<<<dim3(NROWS / 4), dim3(256), 0, stream>>>(x, z4);
  gram_k<<<dim3(NBLK), dim3(256), 0, stream>>>(z4, partial);
  reduce_k<<<dim3(1), dim3(256), 0, stream>>>(partial, out);
}